// Round 14
// baseline (97.964 us; speedup 1.0000x reference)
//
#include <hip/hip_runtime.h>

#define CHUNK 512   // points per wave-pass
#define GRP   32    // group-tracking granularity
#define QB    4     // fallback: queries per block

// ---------------------------------------------------------------------------
// MEASUREMENT ROUND: main is launched 3x (idempotent atomicMin -> identical
// output). dur_us = fixed + 3*T_main; round 11 gave fixed + T_main = 73.4.
// T_main = (dur - 73.4) / 2. Main kernel byte-identical to round 11.
// ---------------------------------------------------------------------------

// init: best[q] = ~0 (don't rely on 0xAA poison semantics for correctness)
__global__ __launch_bounds__(256, 8)
void nn_init_kernel(unsigned long long* __restrict__ best, int B) {
    int i = blockIdx.x * 256 + threadIdx.x;
    if (i < B) best[i] = ~0ULL;
}

// main: one query per LANE; points streamed through SGPRs (wave-uniform
// s_load). readfirstlane keeps the chunk pointer provably wave-uniform.
// Distance-only min (v_sub + v_min3 with |abs| modifiers, 2 chains), group
// tracking at GRP=32, bit-exact epilogue rescan, u64 atomicMin merge
// preserving numpy first-index tie-break exactly.
__global__ __launch_bounds__(256, 8)
void nn_main_kernel(const float* __restrict__ x,
                    const float* __restrict__ pts,
                    unsigned long long* __restrict__ best,
                    int qw_shift)    // nqw = B/64 (pow2)
{
    const int lane = threadIdx.x & 63;
    const int wv = __builtin_amdgcn_readfirstlane((int)(threadIdx.x >> 6));
    const int w  = blockIdx.x * 4 + wv;
    const int qw = w & ((1 << qw_shift) - 1);   // query-wave index
    const int ck = w >> qw_shift;               // point-chunk index

    const int q = (qw << 6) + lane;
    const float xq = x[q];

    const float* __restrict__ pc = pts + (size_t)(unsigned)ck * CHUNK;

    const float inf = __builtin_inff();
    float bdA = inf, bdB = inf, prev = inf;
    int grp = 0;

    #pragma unroll 2
    for (int g = 0; g < CHUNK / GRP; ++g) {
        #pragma unroll
        for (int t = 0; t < GRP / 4; ++t) {
            float p0 = pc[g * GRP + 4 * t + 0];
            float p1 = pc[g * GRP + 4 * t + 1];
            float p2 = pc[g * GRP + 4 * t + 2];
            float p3 = pc[g * GRP + 4 * t + 3];
            bdA = fminf(fminf(fabsf(p0 - xq), fabsf(p1 - xq)), bdA);
            bdB = fminf(fminf(fabsf(p2 - xq), fabsf(p3 - xq)), bdB);
        }
        float cur = fminf(bdA, bdB);
        grp  = (cur < prev) ? g : grp;
        prev = cur;
    }

    const float bd = prev;

    const float4* __restrict__ pg =
        reinterpret_cast<const float4*>(pc + grp * GRP);
    int bi = 0;
    #pragma unroll
    for (int t = GRP / 4 - 1; t >= 0; --t) {   // descending -> first wins
        float4 v = pg[t];
        bi = (fabsf(v.w - xq) == bd) ? 4 * t + 3 : bi;
        bi = (fabsf(v.z - xq) == bd) ? 4 * t + 2 : bi;
        bi = (fabsf(v.y - xq) == bd) ? 4 * t + 1 : bi;
        bi = (fabsf(v.x - xq) == bd) ? 4 * t + 0 : bi;
    }

    const unsigned gidx = (unsigned)(ck * CHUNK + grp * GRP + bi);
    const unsigned long long key =
        ((unsigned long long)__float_as_uint(bd) << 32) | gidx;
    atomicMin(&best[q], key);
}

// gather: out[q] = acc[idx(best[q])]
__global__ __launch_bounds__(256, 8)
void nn_gather_kernel(const unsigned long long* __restrict__ best,
                      const float* __restrict__ acc,
                      float* __restrict__ out, int B) {
    int i = blockIdx.x * 256 + threadIdx.x;
    if (i < B) out[i] = acc[(unsigned)(best[i] & 0xffffffffULL)];
}

// Fallback (round-1 kernel): one query per wave, vector loads. Generic.
__global__ __launch_bounds__(256, 4)
void nn_kernel(const float* __restrict__ x,
               const float* __restrict__ pts,
               const float* __restrict__ acc,
               float* __restrict__ out,
               int B, int N) {
    const int lane = threadIdx.x & 63;
    const int wave = threadIdx.x >> 6;
    const int q    = blockIdx.x * QB + wave;
    if (q >= B) return;

    const float xq = x[q];
    const int G = N >> 2;
    const int J = G >> 6;

    float bd0 = __builtin_inff(), bd1 = __builtin_inff(),
          bd2 = __builtin_inff(), bd3 = __builtin_inff();
    int   bj0 = 0, bj1 = 0, bj2 = 0, bj3 = 0;

    const float4* __restrict__ p4 = reinterpret_cast<const float4*>(pts);

    #pragma unroll 4
    for (int j = 0; j < J; ++j) {
        float4 v = p4[lane + 64 * j];
        float d0 = fabsf(v.x - xq);
        float d1 = fabsf(v.y - xq);
        float d2 = fabsf(v.z - xq);
        float d3 = fabsf(v.w - xq);
        if (d0 < bd0) { bd0 = d0; bj0 = j; }
        if (d1 < bd1) { bd1 = d1; bj1 = j; }
        if (d2 < bd2) { bd2 = d2; bj2 = j; }
        if (d3 < bd3) { bd3 = d3; bj3 = j; }
    }

    unsigned long long key;
    {
        unsigned i0 = (unsigned)(4 * (lane + 64 * bj0) + 0);
        unsigned i1 = (unsigned)(4 * (lane + 64 * bj1) + 1);
        unsigned i2 = (unsigned)(4 * (lane + 64 * bj2) + 2);
        unsigned i3 = (unsigned)(4 * (lane + 64 * bj3) + 3);
        unsigned long long k0 = ((unsigned long long)__float_as_uint(bd0) << 32) | i0;
        unsigned long long k1 = ((unsigned long long)__float_as_uint(bd1) << 32) | i1;
        unsigned long long k2 = ((unsigned long long)__float_as_uint(bd2) << 32) | i2;
        unsigned long long k3 = ((unsigned long long)__float_as_uint(bd3) << 32) | i3;
        key = k0 < k1 ? k0 : k1;
        unsigned long long k23 = k2 < k3 ? k2 : k3;
        key = key < k23 ? key : k23;
    }

    for (int i = J * 256 + lane; i < N; i += 64) {
        float d = fabsf(pts[i] - xq);
        unsigned long long k = ((unsigned long long)__float_as_uint(d) << 32) | (unsigned)i;
        key = key < k ? key : k;
    }

    #pragma unroll
    for (int off = 1; off < 64; off <<= 1) {
        unsigned long long o = __shfl_xor(key, off, 64);
        key = key < o ? key : o;
    }

    if (lane == 0) {
        out[q] = acc[(unsigned)(key & 0xffffffffULL)];
    }
}

extern "C" void kernel_launch(void* const* d_in, const int* in_sizes, int n_in,
                              void* d_out, int out_size, void* d_ws, size_t ws_size,
                              hipStream_t stream) {
    const float* x   = (const float*)d_in[0];
    const float* pts = (const float*)d_in[1];
    const float* acc = (const float*)d_in[2];
    float* out = (float*)d_out;
    const int B = in_sizes[0];
    const int N = in_sizes[1];

    const int nqw = B >> 6;                      // query-waves (64 q each)
    const int nchunk = N / CHUNK;
    const bool pow2 = (nqw > 0) && ((nqw & (nqw - 1)) == 0);
    const bool fast = pow2 && (B % 64 == 0) && (N % CHUNK == 0) &&
                      d_ws != nullptr && ws_size >= (size_t)B * 8;

    if (fast) {
        int qw_shift = 0;
        while ((1 << qw_shift) < nqw) ++qw_shift;
        unsigned long long* best = (unsigned long long*)d_ws;

        hipLaunchKernelGGL(nn_init_kernel, dim3((B + 255) / 256), dim3(256), 0,
                           stream, best, B);
        // Launched 3x on purpose: atomicMin with identical keys is idempotent,
        // so output is unchanged; dur_us gains +2*T_main, exposing the hidden
        // main-kernel time through the harness timer.
        hipLaunchKernelGGL(nn_main_kernel, dim3((nchunk * nqw) / 4), dim3(256),
                           0, stream, x, pts, best, qw_shift);
        hipLaunchKernelGGL(nn_main_kernel, dim3((nchunk * nqw) / 4), dim3(256),
                           0, stream, x, pts, best, qw_shift);
        hipLaunchKernelGGL(nn_main_kernel, dim3((nchunk * nqw) / 4), dim3(256),
                           0, stream, x, pts, best, qw_shift);
        hipLaunchKernelGGL(nn_gather_kernel, dim3((B + 255) / 256), dim3(256),
                           0, stream, best, acc, out, B);
    } else {
        const int blocks = (B + QB - 1) / QB;
        hipLaunchKernelGGL(nn_kernel, dim3(blocks), dim3(256), 0, stream,
                           x, pts, acc, out, B, N);
    }
}